// Round 6
// baseline (305.563 us; speedup 1.0000x reference)
//
#include <hip/hip_runtime.h>
#include <hip/hip_cooperative_groups.h>
#include <hip/hip_bf16.h>

namespace cg = cooperative_groups;

#define N_V   20000
#define KNB   16
#define DCODE 256
#define H1    512
#define H2    1024
#define M3    60000   // N_V * 3

// ws layout (float offsets)
#define OFF_L2P   0          // 8*1024 -> 8192
#define OFF_VPART 8192       // 8*60000 -> 488192
#define OFF_V     488192     // 60000 -> 548192
#define OFF_GV    548192     // 60000 -> 608192
#define OFF_GZ2   608192     // 1024 -> 609216
#define OFF_GZ1   609216     // 512  -> 609728
#define OFF_H1    609728     // 512  -> 610240
#define OFF_H2    610240     // 1024 -> 611264
#define OFF_HC    611264     // 1024 -> 612288
#define OFF_LIST  612288     // 1024 ints -> 613312
#define OFF_CNT   613312     // 2 ints -> 613314
#define OFF_E     613314     // double (613314*4 = 2453256, % 8 == 0)

__device__ inline float frcp(float x) { return __builtin_amdgcn_rcpf(x); }
__device__ inline float frsq(float x) { return __builtin_amdgcn_rsqf(x); }

// branchless fp32 Jacobi rotation (apq==0 degenerates to harmless rotation)
__device__ inline void jrotf(float a[3][3], float v[3][3], int p, int q) {
    float apq = a[p][q];
    float den = 2.0f * apq;
    float sden = copysignf(fmaxf(fabsf(den), 1e-30f), den);
    float theta = (a[q][q] - a[p][p]) * frcp(sden);
    float t = copysignf(1.0f, theta) * frcp(fabsf(theta) + sqrtf(theta * theta + 1.0f));
    float c = frsq(t * t + 1.0f);
    float s = t * c;
    float app = a[p][p], aqq = a[q][q];
    a[p][p] = app - t * apq;
    a[q][q] = aqq + t * apq;
    a[p][q] = 0.0f; a[q][p] = 0.0f;
    int r = 3 - p - q;
    float arp = a[r][p], arq = a[r][q];
    a[r][p] = c * arp - s * arq; a[p][r] = a[r][p];
    a[r][q] = s * arp + c * arq; a[q][r] = a[r][q];
#pragma unroll
    for (int k2 = 0; k2 < 3; ++k2) {
        float vkp = v[k2][p], vkq = v[k2][q];
        v[k2][p] = c * vkp - s * vkq;
        v[k2][q] = s * vkp + c * vkq;
    }
}

// R = V diag(1,1,d) U^T from S (ARAP proper-rotation fit), fp32, fixed 6 sweeps
__device__ void compute_Rf(const float S[3][3], float R[3][3]) {
    float A[3][3], V[3][3];
#pragma unroll
    for (int a = 0; a < 3; ++a)
#pragma unroll
        for (int b = 0; b < 3; ++b) {
            float s = 0.0f;
#pragma unroll
            for (int c = 0; c < 3; ++c) s += S[c][a] * S[c][b];
            A[a][b] = s;
            V[a][b] = (a == b) ? 1.0f : 0.0f;
        }
    for (int sweep = 0; sweep < 6; ++sweep) {
        jrotf(A, V, 0, 1); jrotf(A, V, 0, 2); jrotf(A, V, 1, 2);
    }
    int id[3] = {0, 1, 2};
    if (A[id[0]][id[0]] < A[id[1]][id[1]]) { int t = id[0]; id[0] = id[1]; id[1] = t; }
    if (A[id[0]][id[0]] < A[id[2]][id[2]]) { int t = id[0]; id[0] = id[2]; id[2] = t; }
    if (A[id[1]][id[1]] < A[id[2]][id[2]]) { int t = id[1]; id[1] = id[2]; id[2] = t; }
    float v0[3], v1[3], v2[3];
#pragma unroll
    for (int r = 0; r < 3; ++r) {
        v0[r] = V[r][id[0]]; v1[r] = V[r][id[1]]; v2[r] = V[r][id[2]];
    }
    float u0[3], u1[3], u2[3];
#pragma unroll
    for (int a = 0; a < 3; ++a)
        u0[a] = S[a][0]*v0[0] + S[a][1]*v0[1] + S[a][2]*v0[2];
    float nn0 = u0[0]*u0[0] + u0[1]*u0[1] + u0[2]*u0[2];
    float n0 = sqrtf(nn0);
    if (!(n0 > 1e-20f)) {
#pragma unroll
        for (int a = 0; a < 3; ++a)
#pragma unroll
            for (int c = 0; c < 3; ++c) R[a][c] = (a == c) ? 1.0f : 0.0f;
        return;
    }
    float rn0 = frcp(n0);
#pragma unroll
    for (int a = 0; a < 3; ++a) u0[a] *= rn0;
    float t1[3];
#pragma unroll
    for (int a = 0; a < 3; ++a)
        t1[a] = S[a][0]*v1[0] + S[a][1]*v1[1] + S[a][2]*v1[2];
    float dp = u0[0]*t1[0] + u0[1]*t1[1] + u0[2]*t1[2];
#pragma unroll
    for (int a = 0; a < 3; ++a) t1[a] -= dp * u0[a];
    float n1 = sqrtf(t1[0]*t1[0] + t1[1]*t1[1] + t1[2]*t1[2]);
    if (n1 > 1e-5f * n0) {
        float rn1 = frcp(n1);
#pragma unroll
        for (int a = 0; a < 3; ++a) u1[a] = t1[a] * rn1;
    } else {
        int m = (fabsf(u0[0]) <= fabsf(u0[1]) && fabsf(u0[0]) <= fabsf(u0[2])) ? 0
              : (fabsf(u0[1]) <= fabsf(u0[2]) ? 1 : 2);
        float e[3] = {0.0f, 0.0f, 0.0f}; e[m] = 1.0f;
        float cx[3] = { u0[1]*e[2] - u0[2]*e[1],
                        u0[2]*e[0] - u0[0]*e[2],
                        u0[0]*e[1] - u0[1]*e[0] };
        float rnn = frsq(cx[0]*cx[0] + cx[1]*cx[1] + cx[2]*cx[2]);
#pragma unroll
        for (int a = 0; a < 3; ++a) u1[a] = cx[a] * rnn;
    }
    u2[0] = u0[1]*u1[2] - u0[2]*u1[1];
    u2[1] = u0[2]*u1[0] - u0[0]*u1[2];
    u2[2] = u0[0]*u1[1] - u0[1]*u1[0];
    float d = v0[0]*(v1[1]*v2[2] - v1[2]*v2[1])
            - v0[1]*(v1[0]*v2[2] - v1[2]*v2[0])
            + v0[2]*(v1[0]*v2[1] - v1[1]*v2[0]);
#pragma unroll
    for (int a = 0; a < 3; ++a)
#pragma unroll
        for (int c = 0; c < 3; ++c)
            R[a][c] = v0[a]*u0[c] + v1[a]*u1[c] + d * (v2[a]*u2[c]);
}

__global__ __launch_bounds__(256, 1) void k_mega(
    const float* __restrict__ code, const float* __restrict__ xyz1,
    const float* __restrict__ wmat, const float* __restrict__ W1,
    const float* __restrict__ b1,  const float* __restrict__ W2,
    const float* __restrict__ b2,  const float* __restrict__ W3,
    const float* __restrict__ b3,  const int* __restrict__ nbr,
    const int* __restrict__ nnum,  float* __restrict__ out,
    float* __restrict__ ws)
{
    cg::grid_group grid = cg::this_grid();
    const int bid = blockIdx.x;
    const int t = threadIdx.x;

    __shared__ float red4[4][64];
    __shared__ float h1s[64];
    __shared__ float zp[8][32];
    __shared__ int   scan[256];
    __shared__ int   rlist[128];
    __shared__ float rh[128];
    __shared__ float wsum[4][2];

    // ---- P1: h1 chunk (per dz, redundant over bx), z2 chunk-sum; zero gv/E ----
    {
        const int bx = bid & 31, dz = bid >> 5;
        const int d0 = dz * 64;
        const int ln = t & 63, g4 = t >> 6;
        float acc = 0.f;
        const int r0 = g4 * 64;
#pragma unroll 8
        for (int rr = 0; rr < 64; ++rr)
            acc += code[r0 + rr] * W1[(size_t)(r0 + rr) * H1 + d0 + ln];
        red4[g4][ln] = acc;
        __syncthreads();
        if (g4 == 0) {
            float h = fmaxf(red4[0][ln] + red4[1][ln] + red4[2][ln] + red4[3][ln]
                            + b1[d0 + ln], 0.f);
            h1s[ln] = h;
            if (bx == 0) ws[OFF_H1 + d0 + ln] = h;
        }
        __syncthreads();
        const int col = t & 31, g8 = t >> 5;
        const int m = bx * 32 + col;
        float a2 = 0.f;
        const int dd0 = g8 * 8;
#pragma unroll
        for (int dd = 0; dd < 8; ++dd)
            a2 += h1s[dd0 + dd] * W2[(size_t)(d0 + dd0 + dd) * H2 + m];
        zp[g8][col] = a2;
        __syncthreads();
        if (g8 == 0) {
            float s = 0.f;
#pragma unroll
            for (int p = 0; p < 8; ++p) s += zp[p][col];
            ws[OFF_L2P + dz * H2 + m] = s;
        }
        for (int idx = bid * 256 + t; idx < M3; idx += 65536)
            ws[OFF_GV + idx] = 0.f;
        if (bid == 0 && t == 0)
            *reinterpret_cast<double*>(ws + OFF_E) = 0.0;
    }
    grid.sync();

    // ---- P2: h2 finalize + compaction (block 0 only) ----
    if (bid == 0) {
        float h[4]; int c = 0;
#pragma unroll
        for (int q = 0; q < 4; ++q) {
            int j = t * 4 + q;
            float s = b2[j];
#pragma unroll
            for (int p = 0; p < 8; ++p) s += ws[OFF_L2P + p * H2 + j];
            float hv = fmaxf(s, 0.f);
            ws[OFF_H2 + j] = hv;
            ws[OFF_GZ2 + j] = 0.f;
            h[q] = hv;
            c += (hv > 0.f) ? 1 : 0;
        }
        scan[t] = c;
        __syncthreads();
        for (int off = 1; off < 256; off <<= 1) {
            int x = (t >= off) ? scan[t - off] : 0;
            __syncthreads();
            scan[t] += x;
            __syncthreads();
        }
        int base = scan[t] - c;
        int* list = reinterpret_cast<int*>(&ws[OFF_LIST]);
#pragma unroll
        for (int q = 0; q < 4; ++q) {
            if (h[q] > 0.f) {
                list[base] = t * 4 + q;
                ws[OFF_HC + base] = h[q];
                ++base;
            }
        }
        if (t == 255) *reinterpret_cast<int*>(&ws[OFF_CNT]) = scan[255];
    }
    grid.sync();

    const int cnt = *reinterpret_cast<const int*>(&ws[OFF_CNT]);

    // ---- P3: W3 forward partials (jz fixed per block; row-list loaded once) ----
    {
        const int jz = bid & 7;
        const int bxA = bid >> 3;            // 0..31
        const int per = (cnt + 7) >> 3;
        int s0 = jz * per;
        int s1 = s0 + per; if (s1 > cnt) s1 = cnt;
        const int n = s1 - s0;               // may be <= 0 -> zeros written
        if (t < 128 && t < n) {
            rlist[t] = reinterpret_cast<const int*>(&ws[OFF_LIST])[s0 + t];
            rh[t]    = ws[OFF_HC + s0 + t];
        }
        __syncthreads();
        for (int bx2 = bxA; bx2 < 59; bx2 += 32) {
            int m4 = bx2 * 1024 + t * 4;
            if (m4 < M3) {
                float ax = 0.f, ay = 0.f, az = 0.f, aw = 0.f;
                int ii = 0;
                for (; ii + 7 < n; ii += 8) {
                    float4 wv[8];
#pragma unroll
                    for (int u = 0; u < 8; ++u)
                        wv[u] = *reinterpret_cast<const float4*>(
                            &W3[(size_t)rlist[ii + u] * M3 + m4]);
#pragma unroll
                    for (int u = 0; u < 8; ++u) {
                        float hq = rh[ii + u];
                        ax += hq * wv[u].x; ay += hq * wv[u].y;
                        az += hq * wv[u].z; aw += hq * wv[u].w;
                    }
                }
                for (; ii < n; ++ii) {
                    float hq = rh[ii];
                    float4 wv = *reinterpret_cast<const float4*>(
                        &W3[(size_t)rlist[ii] * M3 + m4]);
                    ax += hq * wv.x; ay += hq * wv.y; az += hq * wv.z; aw += hq * wv.w;
                }
                *reinterpret_cast<float4*>(&ws[OFF_VPART + jz * M3 + m4]) =
                    make_float4(ax, ay, az, aw);
            }
        }
    }
    grid.sync();

    // ---- P4: v = b3 + sum of 8 partials ----
    {
        int i4 = bid * 256 + t;
        if (i4 < M3 / 4) {
            int m = i4 * 4;
            float4 a = *reinterpret_cast<const float4*>(&b3[m]);
#pragma unroll
            for (int jz = 0; jz < 8; ++jz) {
                float4 p = *reinterpret_cast<const float4*>(&ws[OFF_VPART + jz * M3 + m]);
                a.x += p.x; a.y += p.y; a.z += p.z; a.w += p.w;
            }
            *reinterpret_cast<float4*>(&ws[OFF_V + m]) = a;
        }
    }
    grid.sync();

    // ---- P5: ARAP (wave-chunk spread over all blocks) ----
    {
        const float* recon = ws + OFF_V;
        float* gv = ws + OFF_GV;
        const int wv = t >> 6, lane = t & 63;
        const int gw = bid * 4 + wv;                       // 0..1023
        int c = (gw * 313 + 1023) >> 10;                   // candidate chunk
        bool busy = (c < 313) && (((c << 10) / 313) == gw);
        double pv = 0.0;
        int i = c * 64 + lane;
        if (busy && i < N_V) {
            int num = nnum[i]; if (num > KNB) num = KNB;
            float cr0 = xyz1[3*i], cr1 = xyz1[3*i+1], cr2 = xyz1[3*i+2];
            float cd0 = recon[3*i], cd1 = recon[3*i+1], cd2 = recon[3*i+2];
            float S[3][3] = {{0,0,0},{0,0,0},{0,0,0}};
            for (int k = 0; k < num; ++k) {
                int j = nbr[i*KNB + k];
                float w = wmat[i*KNB + k];
                float e0 = xyz1[3*j]  - cr0, e1 = xyz1[3*j+1] - cr1, e2 = xyz1[3*j+2] - cr2;
                float f0 = recon[3*j] - cd0, f1 = recon[3*j+1] - cd1, f2 = recon[3*j+2] - cd2;
                S[0][0] += w*e0*f0; S[0][1] += w*e0*f1; S[0][2] += w*e0*f2;
                S[1][0] += w*e1*f0; S[1][1] += w*e1*f1; S[1][2] += w*e1*f2;
                S[2][0] += w*e2*f0; S[2][1] += w*e2*f1; S[2][2] += w*e2*f2;
            }
            float R[3][3];
            compute_Rf(S, R);
            const float gscale = 2.0f / (float)N_V;
            float own0 = 0.f, own1 = 0.f, own2 = 0.f;
            for (int k = 0; k < num; ++k) {
                int j = nbr[i*KNB + k];
                float w = wmat[i*KNB + k];
                float e0 = xyz1[3*j]  - cr0, e1 = xyz1[3*j+1] - cr1, e2 = xyz1[3*j+2] - cr2;
                float f0 = recon[3*j] - cd0, f1 = recon[3*j+1] - cd1, f2 = recon[3*j+2] - cd2;
                float r0 = f0 - (R[0][0]*e0 + R[0][1]*e1 + R[0][2]*e2);
                float r1 = f1 - (R[1][0]*e0 + R[1][1]*e1 + R[1][2]*e2);
                float r2 = f2 - (R[2][0]*e0 + R[2][1]*e1 + R[2][2]*e2);
                pv += (double)(w * (r0*r0 + r1*r1 + r2*r2));
                float g0 = gscale * w * r0;
                float g1 = gscale * w * r1;
                float g2 = gscale * w * r2;
                atomicAdd(&gv[3*j+0], g0);
                atomicAdd(&gv[3*j+1], g1);
                atomicAdd(&gv[3*j+2], g2);
                own0 += g0; own1 += g1; own2 += g2;
            }
            if (num > 0) {
                atomicAdd(&gv[3*i+0], -own0);
                atomicAdd(&gv[3*i+1], -own1);
                atomicAdd(&gv[3*i+2], -own2);
            }
        }
#pragma unroll
        for (int m = 32; m; m >>= 1) pv += __shfl_xor(pv, m);
        if (busy && lane == 0)
            atomicAdd(reinterpret_cast<double*>(ws + OFF_E), pv);
    }
    grid.sync();

    // ---- P6: gz2 for two live rows per block ----
    {
        int b = bid;
        if (2 * b < cnt) {
            const int* list = reinterpret_cast<const int*>(&ws[OFF_LIST]);
            int j0 = list[2 * b];
            bool has1 = (2 * b + 1 < cnt);
            int j1 = has1 ? list[2 * b + 1] : j0;
            const float4* w3r0 = reinterpret_cast<const float4*>(W3 + (size_t)j0 * M3);
            const float4* w3r1 = reinterpret_cast<const float4*>(W3 + (size_t)j1 * M3);
            const float4* gv4  = reinterpret_cast<const float4*>(ws + OFF_GV);
            float acc0 = 0.f, acc1 = 0.f;
            for (int it = t; it < M3 / 4; it += 256) {
                float4 g = gv4[it];
                float4 a = w3r0[it];
                float4 cc = w3r1[it];
                acc0 += a.x*g.x + a.y*g.y + a.z*g.z + a.w*g.w;
                acc1 += cc.x*g.x + cc.y*g.y + cc.z*g.z + cc.w*g.w;
            }
            for (int m = 32; m; m >>= 1) {
                acc0 += __shfl_xor(acc0, m);
                acc1 += __shfl_xor(acc1, m);
            }
            if ((t & 63) == 0) {
                wsum[t >> 6][0] = acc0;
                wsum[t >> 6][1] = acc1;
            }
            __syncthreads();
            if (t == 0) {
                ws[OFF_GZ2 + j0] = wsum[0][0] + wsum[1][0] + wsum[2][0] + wsum[3][0];
                if (has1)
                    ws[OFF_GZ2 + j1] = wsum[0][1] + wsum[1][1] + wsum[2][1] + wsum[3][1];
            }
        }
    }
    grid.sync();

    // ---- P7: gz1 (wave per row) ----
    {
        const int wv = t >> 6, ln = t & 63;
        const int gw = bid * 4 + wv;
        if (gw < H1) {
            const float* gz2 = ws + OFF_GZ2;
            float acc = 0.f;
#pragma unroll
            for (int it = 0; it < H2 / 64; ++it)
                acc += W2[(size_t)gw * H2 + ln + it * 64] * gz2[ln + it * 64];
            for (int m = 32; m; m >>= 1) acc += __shfl_xor(acc, m);
            if (ln == 0) ws[OFF_GZ1 + gw] = (ws[OFF_H1 + gw] > 0.f) ? acc : 0.f;
        }
    }
    grid.sync();

    // ---- P8: g_code (wave per row) + energy finalize ----
    {
        const int wv = t >> 6, ln = t & 63;
        const int gw = bid * 4 + wv;
        if (gw < DCODE) {
            const float* gz1 = ws + OFF_GZ1;
            float acc = 0.f;
#pragma unroll
            for (int it = 0; it < H1 / 64; ++it)
                acc += W1[(size_t)gw * H1 + ln + it * 64] * gz1[ln + it * 64];
            for (int m = 32; m; m >>= 1) acc += __shfl_xor(acc, m);
            if (ln == 0) out[1 + gw] = acc;
        }
        if (bid == 0 && t == 0) {
            double E = *reinterpret_cast<const double*>(ws + OFF_E);
            out[0] = (float)(-(E / (double)N_V));
        }
    }
}

extern "C" void kernel_launch(void* const* d_in, const int* in_sizes, int n_in,
                              void* d_out, int out_size, void* d_ws, size_t ws_size,
                              hipStream_t stream) {
    const float* code = (const float*)d_in[0];
    const float* xyz1 = (const float*)d_in[1];
    const float* wmat = (const float*)d_in[2];
    const float* W1   = (const float*)d_in[3];
    const float* b1   = (const float*)d_in[4];
    const float* W2   = (const float*)d_in[5];
    const float* b2   = (const float*)d_in[6];
    const float* W3   = (const float*)d_in[7];
    const float* b3   = (const float*)d_in[8];
    const int*   nbr  = (const int*)d_in[9];
    const int*   nnum = (const int*)d_in[10];
    float* out = (float*)d_out;
    float* ws  = (float*)d_ws;

    void* args[] = { (void*)&code, (void*)&xyz1, (void*)&wmat, (void*)&W1,
                     (void*)&b1,   (void*)&W2,   (void*)&b2,   (void*)&W3,
                     (void*)&b3,   (void*)&nbr,  (void*)&nnum, (void*)&out,
                     (void*)&ws };
    hipLaunchCooperativeKernel((const void*)k_mega, dim3(256), dim3(256),
                               args, 0, stream);
}

// Round 7
// 120.068 us; speedup vs baseline: 2.5449x; 2.5449x over previous
//
#include <hip/hip_runtime.h>
#include <hip/hip_bf16.h>

#define N_V   20000
#define KNB   16
#define DCODE 256
#define H1    512
#define H2    1024
#define M3    60000   // N_V * 3

// ws layout (float offsets)
#define OFF_L2P   0          // 8*1024 -> 8192
#define OFF_V     8192       // 60000 -> 68192
#define OFF_GV    68192      // 60000 -> 128192
#define OFF_GZ2P  128192     // 2*1024 partials -> 130240
#define OFF_GZ1   130240     // 512 -> 130752
#define OFF_H1    130752     // 512 -> 131264
#define OFF_H2    131264     // 1024 -> 132288
#define OFF_HC    132288     // 8*128 compacted h2 -> 133312
#define OFF_LIST  133312     // 8*128 ints -> 134336
#define OFF_CNT8  134336     // 8 ints -> 134344
#define OFF_E     134344     // double (byte 537376 % 8 == 0)

// ---------------- layers 1+2 fused; init v=b3, gv=0, E=0 ----------------
// grid (4, 8), block 256
__global__ void k_mlp12(const float* __restrict__ code, const float* __restrict__ W1,
                        const float* __restrict__ b1, const float* __restrict__ W2,
                        const float* __restrict__ b3, float* __restrict__ ws) {
    __shared__ float red[4][64];
    __shared__ float h1s[64];
    int t = threadIdx.x;
    int bx = blockIdx.x, dz = blockIdx.y;
    int d0 = dz * 64;

    int ln = t & 63, g = t >> 6;
    {
        float acc = 0.f;
        int r0 = g * 64;
#pragma unroll 8
        for (int rr = 0; rr < 64; ++rr)
            acc += code[r0 + rr] * W1[(size_t)(r0 + rr) * H1 + d0 + ln];
        red[g][ln] = acc;
    }
    __syncthreads();
    if (g == 0) {
        float h = fmaxf(red[0][ln] + red[1][ln] + red[2][ln] + red[3][ln] + b1[d0 + ln], 0.f);
        h1s[ln] = h;
        if (bx == 0) ws[OFF_H1 + d0 + ln] = h;
    }
    __syncthreads();

    int m = bx * 256 + t;
    float acc = 0.f;
#pragma unroll 8
    for (int dd = 0; dd < 64; ++dd)
        acc += h1s[dd] * W2[(size_t)(d0 + dd) * H2 + m];
    ws[OFF_L2P + dz * H2 + m] = acc;

    // init v = b3, gv = 0 (32 blocks x 256 = 8192 threads)
    int gid = (dz * 4 + bx) * 256 + t;
    for (int idx = gid; idx < M3; idx += 8192) {
        ws[OFF_V + idx]  = b3[idx];
        ws[OFF_GV + idx] = 0.f;
    }
    if (gid == 0) *reinterpret_cast<double*>(ws + OFF_E) = 0.0;
}

// ---------------- W3 forward with per-block compaction, atomic v add ----------------
// grid (59, 8), block 256. Chunk jz covers rows [jz*128, jz*128+128).
__global__ void k_l3p(const float* __restrict__ b2, const float* __restrict__ W3,
                      float* __restrict__ ws) {
    __shared__ float rh[128];
    __shared__ int   rlist[128];
    __shared__ int   scan[128];
    int t = threadIdx.x;
    int jz = blockIdx.y;
    int rbase = jz * 128;

    float hv = 0.f; int flag = 0;
    if (t < 128) {
        float s = b2[rbase + t];
#pragma unroll
        for (int p = 0; p < 8; ++p) s += ws[OFF_L2P + p * H2 + rbase + t];
        hv = fmaxf(s, 0.f);
        flag = (hv > 0.f) ? 1 : 0;
        scan[t] = flag;
    }
    __syncthreads();
    for (int off = 1; off < 128; off <<= 1) {
        int x = 0;
        if (t < 128 && t >= off) x = scan[t - off];
        __syncthreads();
        if (t < 128) scan[t] += x;
        __syncthreads();
    }
    if (t < 128 && flag) {
        int idx = scan[t] - 1;
        rlist[idx] = rbase + t;
        rh[idx] = hv;
    }
    if (blockIdx.x == 0 && t < 128) {
        ws[OFF_H2 + rbase + t] = hv;
        if (flag) {
            reinterpret_cast<int*>(&ws[OFF_LIST])[jz * 128 + scan[t] - 1] = rbase + t;
            ws[OFF_HC + jz * 128 + scan[t] - 1] = hv;
        }
        if (t == 127)
            reinterpret_cast<int*>(&ws[OFF_CNT8])[jz] = scan[127];
    }
    __syncthreads();
    int n = scan[127];

    int m4 = blockIdx.x * 1024 + t * 4;
    if (m4 >= M3) return;
    float ax = 0.f, ay = 0.f, az = 0.f, aw = 0.f;
    int ii = 0;
    for (; ii + 7 < n; ii += 8) {
        float4 wv[8];
#pragma unroll
        for (int u = 0; u < 8; ++u)
            wv[u] = *reinterpret_cast<const float4*>(&W3[(size_t)rlist[ii + u] * M3 + m4]);
#pragma unroll
        for (int u = 0; u < 8; ++u) {
            float h = rh[ii + u];
            ax += h * wv[u].x; ay += h * wv[u].y; az += h * wv[u].z; aw += h * wv[u].w;
        }
    }
    for (; ii < n; ++ii) {
        float h = rh[ii];
        float4 wv = *reinterpret_cast<const float4*>(&W3[(size_t)rlist[ii] * M3 + m4]);
        ax += h * wv.x; ay += h * wv.y; az += h * wv.z; aw += h * wv.w;
    }
    if (n > 0) {
        atomicAdd(&ws[OFF_V + m4 + 0], ax);
        atomicAdd(&ws[OFF_V + m4 + 1], ay);
        atomicAdd(&ws[OFF_V + m4 + 2], az);
        atomicAdd(&ws[OFF_V + m4 + 3], aw);
    }
}

// ---------------- ARAP fused fp32, branchless 6-sweep Jacobi ----------------

__device__ inline float frcp(float x) { return __builtin_amdgcn_rcpf(x); }
__device__ inline float frsq(float x) { return __builtin_amdgcn_rsqf(x); }

__device__ inline void jrotf(float a[3][3], float v[3][3], int p, int q) {
    float apq = a[p][q];
    float den = 2.0f * apq;
    float sden = copysignf(fmaxf(fabsf(den), 1e-30f), den);
    float theta = (a[q][q] - a[p][p]) * frcp(sden);
    float t = copysignf(1.0f, theta) * frcp(fabsf(theta) + sqrtf(theta * theta + 1.0f));
    float c = frsq(t * t + 1.0f);
    float s = t * c;
    float app = a[p][p], aqq = a[q][q];
    a[p][p] = app - t * apq;
    a[q][q] = aqq + t * apq;
    a[p][q] = 0.0f; a[q][p] = 0.0f;
    int r = 3 - p - q;
    float arp = a[r][p], arq = a[r][q];
    a[r][p] = c * arp - s * arq; a[p][r] = a[r][p];
    a[r][q] = s * arp + c * arq; a[q][r] = a[r][q];
#pragma unroll
    for (int k2 = 0; k2 < 3; ++k2) {
        float vkp = v[k2][p], vkq = v[k2][q];
        v[k2][p] = c * vkp - s * vkq;
        v[k2][q] = s * vkp + c * vkq;
    }
}

__device__ void compute_Rf(const float S[3][3], float R[3][3]) {
    float A[3][3], V[3][3];
#pragma unroll
    for (int a = 0; a < 3; ++a)
#pragma unroll
        for (int b = 0; b < 3; ++b) {
            float s = 0.0f;
#pragma unroll
            for (int c = 0; c < 3; ++c) s += S[c][a] * S[c][b];
            A[a][b] = s;
            V[a][b] = (a == b) ? 1.0f : 0.0f;
        }
    for (int sweep = 0; sweep < 6; ++sweep) {
        jrotf(A, V, 0, 1); jrotf(A, V, 0, 2); jrotf(A, V, 1, 2);
    }
    int id[3] = {0, 1, 2};
    if (A[id[0]][id[0]] < A[id[1]][id[1]]) { int t = id[0]; id[0] = id[1]; id[1] = t; }
    if (A[id[0]][id[0]] < A[id[2]][id[2]]) { int t = id[0]; id[0] = id[2]; id[2] = t; }
    if (A[id[1]][id[1]] < A[id[2]][id[2]]) { int t = id[1]; id[1] = id[2]; id[2] = t; }
    float v0[3], v1[3], v2[3];
#pragma unroll
    for (int r = 0; r < 3; ++r) {
        v0[r] = V[r][id[0]]; v1[r] = V[r][id[1]]; v2[r] = V[r][id[2]];
    }
    float u0[3], u1[3], u2[3];
#pragma unroll
    for (int a = 0; a < 3; ++a)
        u0[a] = S[a][0]*v0[0] + S[a][1]*v0[1] + S[a][2]*v0[2];
    float n0 = sqrtf(u0[0]*u0[0] + u0[1]*u0[1] + u0[2]*u0[2]);
    if (!(n0 > 1e-20f)) {
#pragma unroll
        for (int a = 0; a < 3; ++a)
#pragma unroll
            for (int c = 0; c < 3; ++c) R[a][c] = (a == c) ? 1.0f : 0.0f;
        return;
    }
    float rn0 = frcp(n0);
#pragma unroll
    for (int a = 0; a < 3; ++a) u0[a] *= rn0;
    float t1[3];
#pragma unroll
    for (int a = 0; a < 3; ++a)
        t1[a] = S[a][0]*v1[0] + S[a][1]*v1[1] + S[a][2]*v1[2];
    float dp = u0[0]*t1[0] + u0[1]*t1[1] + u0[2]*t1[2];
#pragma unroll
    for (int a = 0; a < 3; ++a) t1[a] -= dp * u0[a];
    float n1 = sqrtf(t1[0]*t1[0] + t1[1]*t1[1] + t1[2]*t1[2]);
    if (n1 > 1e-5f * n0) {
        float rn1 = frcp(n1);
#pragma unroll
        for (int a = 0; a < 3; ++a) u1[a] = t1[a] * rn1;
    } else {
        int m = (fabsf(u0[0]) <= fabsf(u0[1]) && fabsf(u0[0]) <= fabsf(u0[2])) ? 0
              : (fabsf(u0[1]) <= fabsf(u0[2]) ? 1 : 2);
        float e[3] = {0.0f, 0.0f, 0.0f}; e[m] = 1.0f;
        float cx[3] = { u0[1]*e[2] - u0[2]*e[1],
                        u0[2]*e[0] - u0[0]*e[2],
                        u0[0]*e[1] - u0[1]*e[0] };
        float rnn = frsq(cx[0]*cx[0] + cx[1]*cx[1] + cx[2]*cx[2]);
#pragma unroll
        for (int a = 0; a < 3; ++a) u1[a] = cx[a] * rnn;
    }
    u2[0] = u0[1]*u1[2] - u0[2]*u1[1];
    u2[1] = u0[2]*u1[0] - u0[0]*u1[2];
    u2[2] = u0[0]*u1[1] - u0[1]*u1[0];
    float d = v0[0]*(v1[1]*v2[2] - v1[2]*v2[1])
            - v0[1]*(v1[0]*v2[2] - v1[2]*v2[0])
            + v0[2]*(v1[0]*v2[1] - v1[1]*v2[0]);
#pragma unroll
    for (int a = 0; a < 3; ++a)
#pragma unroll
        for (int c = 0; c < 3; ++c)
            R[a][c] = v0[a]*u0[c] + v1[a]*u1[c] + d * (v2[a]*u2[c]);
}

// grid 313, block 64: single gather pass; er/ed stashed in registers
__global__ void k_arap(const float* __restrict__ xyz1, const float* __restrict__ wmat,
                       const int* __restrict__ nbr, const int* __restrict__ nnum,
                       float* __restrict__ ws) {
    const float* recon = ws + OFF_V;
    float* gv = ws + OFF_GV;
    int i = blockIdx.x * 64 + threadIdx.x;
    double pv = 0.0;
    if (i < N_V) {
        int num = nnum[i]; if (num > KNB) num = KNB;
        float cr0 = xyz1[3*i], cr1 = xyz1[3*i+1], cr2 = xyz1[3*i+2];
        float cd0 = recon[3*i], cd1 = recon[3*i+1], cd2 = recon[3*i+2];
        float er[KNB][3], ed[KNB][3], wk[KNB];
        int   jn[KNB];
        float S[3][3] = {{0,0,0},{0,0,0},{0,0,0}};
#pragma unroll
        for (int k = 0; k < KNB; ++k) {
            bool live = (k < num);
            int j = live ? nbr[i*KNB + k] : i;
            float w = live ? wmat[i*KNB + k] : 0.f;
            jn[k] = j; wk[k] = w;
            float e0 = xyz1[3*j]  - cr0, e1 = xyz1[3*j+1] - cr1, e2 = xyz1[3*j+2] - cr2;
            float f0 = recon[3*j] - cd0, f1 = recon[3*j+1] - cd1, f2 = recon[3*j+2] - cd2;
            er[k][0] = e0; er[k][1] = e1; er[k][2] = e2;
            ed[k][0] = f0; ed[k][1] = f1; ed[k][2] = f2;
            S[0][0] += w*e0*f0; S[0][1] += w*e0*f1; S[0][2] += w*e0*f2;
            S[1][0] += w*e1*f0; S[1][1] += w*e1*f1; S[1][2] += w*e1*f2;
            S[2][0] += w*e2*f0; S[2][1] += w*e2*f1; S[2][2] += w*e2*f2;
        }
        float R[3][3];
        compute_Rf(S, R);
        const float gscale = 2.0f / (float)N_V;
        float own0 = 0.f, own1 = 0.f, own2 = 0.f;
#pragma unroll
        for (int k = 0; k < KNB; ++k) {
            if (k < num) {
                float w = wk[k];
                float r0 = ed[k][0] - (R[0][0]*er[k][0] + R[0][1]*er[k][1] + R[0][2]*er[k][2]);
                float r1 = ed[k][1] - (R[1][0]*er[k][0] + R[1][1]*er[k][1] + R[1][2]*er[k][2]);
                float r2 = ed[k][2] - (R[2][0]*er[k][0] + R[2][1]*er[k][1] + R[2][2]*er[k][2]);
                pv += (double)(w * (r0*r0 + r1*r1 + r2*r2));
                float g0 = gscale * w * r0;
                float g1 = gscale * w * r1;
                float g2 = gscale * w * r2;
                int j = jn[k];
                atomicAdd(&gv[3*j+0], g0);
                atomicAdd(&gv[3*j+1], g1);
                atomicAdd(&gv[3*j+2], g2);
                own0 += g0; own1 += g1; own2 += g2;
            }
        }
        if (num > 0) {
            atomicAdd(&gv[3*i+0], -own0);
            atomicAdd(&gv[3*i+1], -own1);
            atomicAdd(&gv[3*i+2], -own2);
        }
    }
#pragma unroll
    for (int m = 32; m; m >>= 1) pv += __shfl_xor(pv, m);
    if (threadIdx.x == 0)
        atomicAdd(reinterpret_cast<double*>(ws + OFF_E), pv);
}

// ---------------- backward ----------------

// grid (256, 2), block 256: pair of live rows x column half; partials to GZ2P
__global__ void k_gh2(const float* __restrict__ W3, float* __restrict__ ws) {
    const int* cnt8 = reinterpret_cast<const int*>(&ws[OFF_CNT8]);
    int pre[9];
    pre[0] = 0;
#pragma unroll
    for (int c = 0; c < 8; ++c) pre[c + 1] = pre[c] + cnt8[c];
    int total = pre[8];
    int g0 = 2 * blockIdx.x;
    if (g0 >= total) return;
    int g1 = g0 + 1;
    bool has1 = (g1 < total);

    const int* list = reinterpret_cast<const int*>(&ws[OFF_LIST]);
    int c0 = 0, c1 = 0;
#pragma unroll
    for (int c = 0; c < 8; ++c) {
        if (g0 >= pre[c + 1]) c0 = c + 1;
        if (g1 >= pre[c + 1]) c1 = c + 1;
    }
    int j0 = list[c0 * 128 + (g0 - pre[c0])];
    int j1 = has1 ? list[c1 * 128 + (g1 - pre[c1])] : j0;

    int half = blockIdx.y;
    int start = half * 7500;        // float4 units
    int end = start + 7500;
    const float4* w3r0 = reinterpret_cast<const float4*>(W3 + (size_t)j0 * M3);
    const float4* w3r1 = reinterpret_cast<const float4*>(W3 + (size_t)j1 * M3);
    const float4* gv4  = reinterpret_cast<const float4*>(ws + OFF_GV);
    int t = threadIdx.x;

    float a00 = 0.f, a01 = 0.f, a02 = 0.f, a03 = 0.f;
    float a10 = 0.f, a11 = 0.f, a12 = 0.f, a13 = 0.f;
    int it = start + t;
    for (; it + 768 < end; it += 1024) {
        float4 g0v = gv4[it],        g1v = gv4[it + 256],
               g2v = gv4[it + 512],  g3v = gv4[it + 768];
        float4 p0 = w3r0[it],        p1 = w3r0[it + 256],
               p2 = w3r0[it + 512],  p3 = w3r0[it + 768];
        float4 q0 = w3r1[it],        q1 = w3r1[it + 256],
               q2 = w3r1[it + 512],  q3 = w3r1[it + 768];
        a00 += p0.x*g0v.x + p0.y*g0v.y + p0.z*g0v.z + p0.w*g0v.w;
        a01 += p1.x*g1v.x + p1.y*g1v.y + p1.z*g1v.z + p1.w*g1v.w;
        a02 += p2.x*g2v.x + p2.y*g2v.y + p2.z*g2v.z + p2.w*g2v.w;
        a03 += p3.x*g3v.x + p3.y*g3v.y + p3.z*g3v.z + p3.w*g3v.w;
        a10 += q0.x*g0v.x + q0.y*g0v.y + q0.z*g0v.z + q0.w*g0v.w;
        a11 += q1.x*g1v.x + q1.y*g1v.y + q1.z*g1v.z + q1.w*g1v.w;
        a12 += q2.x*g2v.x + q2.y*g2v.y + q2.z*g2v.z + q2.w*g2v.w;
        a13 += q3.x*g3v.x + q3.y*g3v.y + q3.z*g3v.z + q3.w*g3v.w;
    }
    for (; it < end; it += 256) {
        float4 g = gv4[it];
        float4 p = w3r0[it];
        float4 q = w3r1[it];
        a00 += p.x*g.x + p.y*g.y + p.z*g.z + p.w*g.w;
        a10 += q.x*g.x + q.y*g.y + q.z*g.z + q.w*g.w;
    }
    float acc0 = a00 + a01 + a02 + a03;
    float acc1 = a10 + a11 + a12 + a13;
    for (int m = 32; m; m >>= 1) {
        acc0 += __shfl_xor(acc0, m);
        acc1 += __shfl_xor(acc1, m);
    }
    __shared__ float wsum[4][2];
    if ((t & 63) == 0) {
        wsum[t >> 6][0] = acc0;
        wsum[t >> 6][1] = acc1;
    }
    __syncthreads();
    if (t == 0) {
        float* gz2p = ws + OFF_GZ2P + half * H2;
        gz2p[j0] = wsum[0][0] + wsum[1][0] + wsum[2][0] + wsum[3][0];
        if (has1)
            gz2p[j1] = wsum[0][1] + wsum[1][1] + wsum[2][1] + wsum[3][1];
    }
}

// grid 128, block 256 (wave per row): g_z1[i] = (h1[i]>0) * dot(W2[i,:], gz2)
// gz2[j] = (h2[j]>0) ? gz2p[0][j]+gz2p[1][j] : 0
__global__ void k_gh1(const float* __restrict__ W2, float* __restrict__ ws) {
    int wv = threadIdx.x >> 6, ln = threadIdx.x & 63;
    int i = blockIdx.x * 4 + wv;  // < 512
    float acc = 0.f;
#pragma unroll
    for (int it = 0; it < H2 / 64; ++it) {
        int jj = ln + it * 64;
        float gz2 = (ws[OFF_H2 + jj] > 0.f)
                  ? (ws[OFF_GZ2P + jj] + ws[OFF_GZ2P + H2 + jj]) : 0.f;
        acc += W2[(size_t)i * H2 + jj] * gz2;
    }
    for (int m = 32; m; m >>= 1) acc += __shfl_xor(acc, m);
    if (ln == 0) ws[OFF_GZ1 + i] = (ws[OFF_H1 + i] > 0.f) ? acc : 0.f;
}

// grid 64, block 256 (wave per row): out[1+d] = dot(W1[d,:], g_z1); out[0] = -E/N
__global__ void k_gcode(const float* __restrict__ W1, float* __restrict__ ws,
                        float* __restrict__ out) {
    int wv = threadIdx.x >> 6, ln = threadIdx.x & 63;
    int d = blockIdx.x * 4 + wv;  // < 256
    const float* gz1 = ws + OFF_GZ1;
    float acc = 0.f;
#pragma unroll
    for (int it = 0; it < H1 / 64; ++it) {
        int ii = ln + it * 64;
        acc += W1[(size_t)d * H1 + ii] * gz1[ii];
    }
    for (int m = 32; m; m >>= 1) acc += __shfl_xor(acc, m);
    if (ln == 0) out[1 + d] = acc;
    if (blockIdx.x == 0 && threadIdx.x == 0) {
        double E = *reinterpret_cast<const double*>(ws + OFF_E);
        out[0] = (float)(-(E / (double)N_V));
    }
}

extern "C" void kernel_launch(void* const* d_in, const int* in_sizes, int n_in,
                              void* d_out, int out_size, void* d_ws, size_t ws_size,
                              hipStream_t stream) {
    const float* code = (const float*)d_in[0];
    const float* xyz1 = (const float*)d_in[1];
    const float* wmat = (const float*)d_in[2];
    const float* W1   = (const float*)d_in[3];
    const float* b1   = (const float*)d_in[4];
    const float* W2   = (const float*)d_in[5];
    const float* b2   = (const float*)d_in[6];
    const float* W3   = (const float*)d_in[7];
    const float* b3   = (const float*)d_in[8];
    const int*   nbr  = (const int*)d_in[9];
    const int*   nnum = (const int*)d_in[10];
    float* out = (float*)d_out;
    float* ws  = (float*)d_ws;

    k_mlp12<<<dim3(4, 8),   256, 0, stream>>>(code, W1, b1, W2, b3, ws);
    k_l3p  <<<dim3(59, 8),  256, 0, stream>>>(b2, W3, ws);
    k_arap <<<313,           64, 0, stream>>>(xyz1, wmat, nbr, nnum, ws);
    k_gh2  <<<dim3(256, 2), 256, 0, stream>>>(W3, ws);
    k_gh1  <<<128,          256, 0, stream>>>(W2, ws);
    k_gcode<<<64,           256, 0, stream>>>(W1, ws, out);
}